// Round 2
// baseline (170807.739 us; speedup 1.0000x reference)
//
#include <hip/hip_runtime.h>
#include <stdint.h>

#define TSTEPS 512
#define BATCH  64
#define ISZ    512
#define HSZ    1024
#define GSZ    4096
#define NB     256
#define NT     256
#define NGRP   8          // barrier groups (== XCDs under round-robin dispatch)
#define GRPSZ  (NB / NGRP)
#define LSTRIDE 16        // ints per barrier line (64 B)

static constexpr size_t OFF_XPREV = (size_t)TSTEPS * BATCH * HSZ;      // 33554432
static constexpr size_t OFF_H     = OFF_XPREV + (size_t)BATCH * 1024;  // x_prev padded to max(I,H)=1024
static constexpr size_t OFF_HP    = OFF_H  + (size_t)BATCH * HSZ;
static constexpr size_t OFF_C     = OFF_HP + (size_t)BATCH * HSZ;
static constexpr size_t OFF_M     = OFF_C  + (size_t)BATCH * HSZ;
static constexpr size_t OFF_REG   = OFF_M  + (size_t)BATCH * GSZ;

#define TH_RAW 0.1f
#define TH_QNT 0.1015625f   // quantize(0.1, Q8.8) = rint(25.6)/256 = 26/256

// Q8.8 fake-quantize: clip(rint(x*256), -32768, 32767)/256  (rintf = RTNE = jnp.round)
__device__ __forceinline__ float qA(float x) {
  float v = rintf(x * 256.0f);
  v = fminf(fmaxf(v, -32768.0f), 32767.0f);
  return v * 0.00390625f;
}
// Q2.8 fake-quantize: clip(rint(x*256), -512, 511)/256
__device__ __forceinline__ float qN(float x) {
  float v = rintf(x * 256.0f);
  v = fminf(fmaxf(v, -512.0f), 511.0f);
  return v * 0.00390625f;
}
__device__ __forceinline__ float sigm(float x) { return 1.0f / (1.0f + expf(-x)); }

// ---------------------------------------------------------------------------
// Phase A: quantize x, sequential x-delta scan (exact fixed-point; independent
// of the recurrence). One thread per (b,i). Writes dx[T,B,I] and x_prev output.
// ---------------------------------------------------------------------------
__global__ __launch_bounds__(256) void xscan_kernel(const float* __restrict__ x,
                                                    float* __restrict__ dx,
                                                    float* __restrict__ out_xprev) {
  const int gid = blockIdx.x * blockDim.x + threadIdx.x;  // 0..32767 == b*512+i
  float xp = 0.0f;
  #pragma unroll 8
  for (int t = 0; t < TSTEPS; t++) {
    float xq = qA(x[(size_t)t * (BATCH * ISZ) + gid]);
    float d  = xq - xp;
    float da = fabsf(d);
    dx[(size_t)t * (BATCH * ISZ) + gid] = (da < TH_QNT) ? 0.0f : d;
    if (da >= TH_RAW) xp = xq;
  }
  const int b = gid >> 9;
  const int i = gid & 511;
  out_xprev[(size_t)b * 1024 + i]       = xp;    // first I columns
  out_xprev[(size_t)b * 1024 + 512 + i] = 0.0f;  // zero pad to max(I,H)
}

// ---------------------------------------------------------------------------
// Hierarchical grid barrier (2-level, XCD-aware).
// bar layout (ints): cnt[8 lines] | gcnt line | gen[8 lines]
// Level 1: 32 arrivals on an XCD-local line. Level 2: 8 arrivals on one line.
// Release: final arriver resets counters, then release-stores 8 gen lines;
// each block polls only its own (XCD-local) gen line.
// Release chain = ACQ_REL RMW sequence at agent scope -> cross-XCD dh
// visibility identical to the (validated) single-level version.
// ---------------------------------------------------------------------------
__device__ __forceinline__ void gbar(int* bar, int e) {
  __syncthreads();
  if (threadIdx.x == 0) {
    const int g = blockIdx.x & (NGRP - 1);
    int* cnt  = bar + g * LSTRIDE;
    int* gcnt = bar + NGRP * LSTRIDE;
    int* gen  = bar + (NGRP + 1) * LSTRIDE + g * LSTRIDE;
    int prev = __hip_atomic_fetch_add(cnt, 1, __ATOMIC_ACQ_REL, __HIP_MEMORY_SCOPE_AGENT);
    if (prev == GRPSZ - 1) {                       // last arrival in this group
      int gprev = __hip_atomic_fetch_add(gcnt, 1, __ATOMIC_ACQ_REL, __HIP_MEMORY_SCOPE_AGENT);
      if (gprev == NGRP - 1) {                     // last group: reset + release all
        __hip_atomic_store(gcnt, 0, __ATOMIC_RELAXED, __HIP_MEMORY_SCOPE_AGENT);
        #pragma unroll
        for (int g2 = 0; g2 < NGRP; g2++)
          __hip_atomic_store(bar + g2 * LSTRIDE, 0, __ATOMIC_RELAXED, __HIP_MEMORY_SCOPE_AGENT);
        #pragma unroll
        for (int g2 = 0; g2 < NGRP; g2++)
          __hip_atomic_store(bar + (NGRP + 1) * LSTRIDE + g2 * LSTRIDE, e,
                             __ATOMIC_RELEASE, __HIP_MEMORY_SCOPE_AGENT);
        __syncthreads();
        return;
      }
    }
    while (__hip_atomic_load(gen, __ATOMIC_ACQUIRE, __HIP_MEMORY_SCOPE_AGENT) < e) {
      __builtin_amdgcn_s_sleep(2);
    }
  }
  __syncthreads();
}

// ---------------------------------------------------------------------------
// Phase B: persistent scan. 256 blocks x 256 threads = 65536 = B*H sites.
// Thread (b,j) owns c, h_prev, m[4 gates] in REGISTERS for all 512 steps.
// ---------------------------------------------------------------------------
__global__ __launch_bounds__(NT, 1) void scan_kernel(
    const float* __restrict__ dx, const float* __restrict__ w_ih,
    const float* __restrict__ w_hh, const float* __restrict__ b_ih,
    const float* __restrict__ b_hh, float* __restrict__ out,
    float* __restrict__ dh0, float* __restrict__ dh1,
    float* __restrict__ partials, int* bar) {
  const int tid = threadIdx.x;
  const int jj  = tid & 3;
  const int b   = tid >> 2;                 // 0..63
  const int j   = blockIdx.x * 4 + jj;      // 0..1023
  const int g0 = j, g1 = j + HSZ, g2 = j + 2 * HSZ, g3 = j + 3 * HSZ;

  float m0 = b_ih[g0] + b_hh[g0];
  float m1 = b_ih[g1] + b_hh[g1];
  float m2 = b_ih[g2] + b_hh[g2];
  float m3 = b_ih[g3] + b_hh[g3];
  float c = 0.0f, hp = 0.0f, h = 0.0f, regacc = 0.0f;

  // dh for step 0 is identically zero (h0 == h_prev0 == 0)
  dh0[(size_t)b * HSZ + j] = 0.0f;
  int epoch = 1;
  gbar(bar, epoch); epoch++;

  const float4* __restrict__ wi0 = (const float4*)(w_ih + (size_t)g0 * ISZ);
  const float4* __restrict__ wi1 = (const float4*)(w_ih + (size_t)g1 * ISZ);
  const float4* __restrict__ wi2 = (const float4*)(w_ih + (size_t)g2 * ISZ);
  const float4* __restrict__ wi3 = (const float4*)(w_ih + (size_t)g3 * ISZ);
  const float4* __restrict__ wh0 = (const float4*)(w_hh + (size_t)g0 * HSZ);
  const float4* __restrict__ wh1 = (const float4*)(w_hh + (size_t)g1 * HSZ);
  const float4* __restrict__ wh2 = (const float4*)(w_hh + (size_t)g2 * HSZ);
  const float4* __restrict__ wh3 = (const float4*)(w_hh + (size_t)g3 * HSZ);

  for (int t = 0; t < TSTEPS; t++) {
    float a0 = 0.f, a1 = 0.f, a2 = 0.f, a3 = 0.f;
    {  // x contribution: dx[t,b,:] @ w_ih rows (K=512)
      const float4* __restrict__ xr = (const float4*)(dx + ((size_t)t * BATCH + b) * ISZ);
      #pragma unroll 8
      for (int k = 0; k < ISZ / 4; k++) {
        float4 xv = xr[k]; float4 wv;
        wv = wi0[k]; a0 = fmaf(xv.x, wv.x, fmaf(xv.y, wv.y, fmaf(xv.z, wv.z, fmaf(xv.w, wv.w, a0))));
        wv = wi1[k]; a1 = fmaf(xv.x, wv.x, fmaf(xv.y, wv.y, fmaf(xv.z, wv.z, fmaf(xv.w, wv.w, a1))));
        wv = wi2[k]; a2 = fmaf(xv.x, wv.x, fmaf(xv.y, wv.y, fmaf(xv.z, wv.z, fmaf(xv.w, wv.w, a2))));
        wv = wi3[k]; a3 = fmaf(xv.x, wv.x, fmaf(xv.y, wv.y, fmaf(xv.z, wv.z, fmaf(xv.w, wv.w, a3))));
      }
    }
    {  // h contribution: dh[b,:] @ w_hh rows (K=1024)
      const float* dhb = (t & 1) ? dh1 : dh0;
      const float4* __restrict__ hr = (const float4*)(dhb + (size_t)b * HSZ);
      #pragma unroll 8
      for (int k = 0; k < HSZ / 4; k++) {
        float4 hv = hr[k]; float4 wv;
        wv = wh0[k]; a0 = fmaf(hv.x, wv.x, fmaf(hv.y, wv.y, fmaf(hv.z, wv.z, fmaf(hv.w, wv.w, a0))));
        wv = wh1[k]; a1 = fmaf(hv.x, wv.x, fmaf(hv.y, wv.y, fmaf(hv.z, wv.z, fmaf(hv.w, wv.w, a1))));
        wv = wh2[k]; a2 = fmaf(hv.x, wv.x, fmaf(hv.y, wv.y, fmaf(hv.z, wv.z, fmaf(hv.w, wv.w, a2))));
        wv = wh3[k]; a3 = fmaf(hv.x, wv.x, fmaf(hv.y, wv.y, fmaf(hv.z, wv.z, fmaf(hv.w, wv.w, a3))));
      }
    }
    m0 += a0; m1 += a1; m2 += a2; m3 += a3;

    float pi = qA(m0), pf = qA(m1), pg = qA(m2), po = qA(m3);
    float gi = qN(sigm(pi));
    float gf = qN(sigm(pf));
    float gg = qN(tanhf(pg));
    float go = qN(sigm(po));
    float cn = c * gf + gi * gg;
    c = qA(cn);
    float ct = qN(tanhf(c));
    h = qA(go * ct);
    out[(size_t)t * (BATCH * HSZ) + (size_t)b * HSZ + j] = h;

    if (t < TSTEPS - 1) {  // produce dh for step t+1 (reference computes it at start of t+1)
      float d  = h - hp;
      float da = fabsf(d);
      float dm = (da < TH_QNT) ? 0.0f : d;
      float* nbuf = (t & 1) ? dh0 : dh1;
      nbuf[(size_t)b * HSZ + j] = dm;
      if (da >= TH_RAW) hp = h;
      regacc += fabsf(dm);
    }
    gbar(bar, epoch); epoch++;
  }

  // final state dump (carry after step T-1)
  out[OFF_H  + (size_t)b * HSZ + j] = h;
  out[OFF_HP + (size_t)b * HSZ + j] = hp;
  out[OFF_C  + (size_t)b * HSZ + j] = c;
  out[OFF_M  + (size_t)b * GSZ + g0] = m0;
  out[OFF_M  + (size_t)b * GSZ + g1] = m1;
  out[OFF_M  + (size_t)b * GSZ + g2] = m2;
  out[OFF_M  + (size_t)b * GSZ + g3] = m3;

  // deterministic reg reduction: block tree-reduce -> partials -> block 0
  __shared__ float red[NT];
  red[tid] = regacc;
  __syncthreads();
  for (int s = NT / 2; s > 0; s >>= 1) {
    if (tid < s) red[tid] += red[tid + s];
    __syncthreads();
  }
  if (tid == 0) partials[blockIdx.x] = red[0];
  gbar(bar, epoch); epoch++;
  if (blockIdx.x == 0) {
    red[tid] = partials[tid];  // NT == NB == 256
    __syncthreads();
    for (int s = NT / 2; s > 0; s >>= 1) {
      if (tid < s) red[tid] += red[tid + s];
      __syncthreads();
    }
    if (tid == 0) out[OFF_REG] = red[0];
  }
}

// ---------------------------------------------------------------------------
extern "C" void kernel_launch(void* const* d_in, const int* in_sizes, int n_in,
                              void* d_out, int out_size, void* d_ws, size_t ws_size,
                              hipStream_t stream) {
  const float* x    = (const float*)d_in[0];
  const float* w_ih = (const float*)d_in[1];
  const float* w_hh = (const float*)d_in[2];
  const float* b_ih = (const float*)d_in[3];
  const float* b_hh = (const float*)d_in[4];
  float* out = (float*)d_out;

  const size_t dx_elems = (size_t)TSTEPS * BATCH * ISZ;  // 16,777,216 floats = 64 MiB
  float* dx       = (float*)d_ws;
  float* dh0      = dx + dx_elems;
  float* dh1      = dh0 + (size_t)BATCH * HSZ;
  float* partials = dh1 + (size_t)BATCH * HSZ;
  int*   bar      = (int*)(partials + NB);
  const int bar_ints = (NGRP + 1 + NGRP) * LSTRIDE;  // cnt lines | gcnt | gen lines
  size_t needed = (size_t)((char*)(bar + bar_ints) - (char*)d_ws);
  if (ws_size < needed) return;  // fail validation cleanly rather than corrupt memory

  hipMemsetAsync(bar, 0, bar_ints * sizeof(int), stream);  // barrier state must start at 0
  xscan_kernel<<<128, 256, 0, stream>>>(x, dx, out + OFF_XPREV);
  scan_kernel<<<NB, NT, 0, stream>>>(dx, w_ih, w_hh, b_ih, b_hh, out,
                                     dh0, dh1, partials, bar);
}

// Round 3
// 101366.528 us; speedup vs baseline: 1.6851x; 1.6851x over previous
//
#include <hip/hip_runtime.h>
#include <stdint.h>

#define TSTEPS 512
#define BATCH  64
#define ISZ    512
#define HSZ    1024
#define GSZ    4096
#define NB     256
#define NT     256

static constexpr size_t OFF_XPREV = (size_t)TSTEPS * BATCH * HSZ;      // 33554432
static constexpr size_t OFF_H     = OFF_XPREV + (size_t)BATCH * 1024;  // x_prev padded to max(I,H)=1024
static constexpr size_t OFF_HP    = OFF_H  + (size_t)BATCH * HSZ;
static constexpr size_t OFF_C     = OFF_HP + (size_t)BATCH * HSZ;
static constexpr size_t OFF_M     = OFF_C  + (size_t)BATCH * HSZ;
static constexpr size_t OFF_REG   = OFF_M  + (size_t)BATCH * GSZ;

#define TH_RAW 0.1f
#define TH_QNT 0.1015625f   // quantize(0.1, Q8.8) = rint(25.6)/256 = 26/256

// Q8.8 fake-quantize: clip(rint(x*256), -32768, 32767)/256  (rintf = RTNE = jnp.round)
__device__ __forceinline__ float qA(float x) {
  float v = rintf(x * 256.0f);
  v = fminf(fmaxf(v, -32768.0f), 32767.0f);
  return v * 0.00390625f;
}
// Q2.8 fake-quantize: clip(rint(x*256), -512, 511)/256
__device__ __forceinline__ float qN(float x) {
  float v = rintf(x * 256.0f);
  v = fminf(fmaxf(v, -512.0f), 511.0f);
  return v * 0.00390625f;
}
__device__ __forceinline__ float sigm(float x) { return 1.0f / (1.0f + expf(-x)); }

// ---------------------------------------------------------------------------
// Phase A: quantize x, sequential x-delta scan (exact fixed-point; independent
// of the recurrence). One thread per (b,i). Writes dx[T,B,I] and x_prev output.
// ---------------------------------------------------------------------------
__global__ __launch_bounds__(256) void xscan_kernel(const float* __restrict__ x,
                                                    float* __restrict__ dx,
                                                    float* __restrict__ out_xprev) {
  const int gid = blockIdx.x * blockDim.x + threadIdx.x;  // 0..32767 == b*512+i
  float xp = 0.0f;
  #pragma unroll 8
  for (int t = 0; t < TSTEPS; t++) {
    float xq = qA(x[(size_t)t * (BATCH * ISZ) + gid]);
    float d  = xq - xp;
    float da = fabsf(d);
    dx[(size_t)t * (BATCH * ISZ) + gid] = (da < TH_QNT) ? 0.0f : d;
    if (da >= TH_RAW) xp = xq;
  }
  const int b = gid >> 9;
  const int i = gid & 511;
  out_xprev[(size_t)b * 1024 + i]       = xp;    // first I columns
  out_xprev[(size_t)b * 1024 + 512 + i] = 0.0f;  // zero pad to max(I,H)
}

// ---------------------------------------------------------------------------
// Flag-array grid barrier: NO read-modify-writes anywhere.
// flags[NB]: block i's private word. Arrival = one release-store of epoch e
// (stores merge at the coherence point; no exclusive-ownership chain).
// Wait = all NT threads poll flags[tid] with RELAXED agent loads (1KB,
// coalesced, sc1 path) + __syncthreads_and. One ACQUIRE load afterwards
// provides cross-XCD visibility of dh written before the release-stores
// (same agent-scope release/acquire pairing that validated in rounds 1-2).
// ---------------------------------------------------------------------------
__device__ __forceinline__ void gbar(int* flags, int e) {
  __syncthreads();
  if (threadIdx.x == 0) {
    __hip_atomic_store(&flags[blockIdx.x], e, __ATOMIC_RELEASE, __HIP_MEMORY_SCOPE_AGENT);
  }
  int ok;
  do {
    int f = __hip_atomic_load(&flags[threadIdx.x], __ATOMIC_RELAXED, __HIP_MEMORY_SCOPE_AGENT);
    ok = __syncthreads_and(f >= e);
    if (!ok) __builtin_amdgcn_s_sleep(1);
  } while (!ok);
  __hip_atomic_load(&flags[threadIdx.x], __ATOMIC_ACQUIRE, __HIP_MEMORY_SCOPE_AGENT);
  __syncthreads();
}

// ---------------------------------------------------------------------------
// Phase B: persistent scan. 256 blocks x 256 threads = 65536 = B*H sites.
// Thread (b,j) owns c, h_prev, m[4 gates] in REGISTERS for all 512 steps.
// Block = 4 hidden units x all 64 batches -> 16 weight rows (96KB) read by
// exactly this block (chip-wide weight traffic is the 24MB/step minimum).
// ---------------------------------------------------------------------------
__global__ __launch_bounds__(NT, 1) void scan_kernel(
    const float* __restrict__ dx, const float* __restrict__ w_ih,
    const float* __restrict__ w_hh, const float* __restrict__ b_ih,
    const float* __restrict__ b_hh, float* __restrict__ out,
    float* __restrict__ dh0, float* __restrict__ dh1,
    float* __restrict__ partials, int* flags) {
  const int tid = threadIdx.x;
  const int jj  = tid & 3;
  const int b   = tid >> 2;                 // 0..63
  const int j   = blockIdx.x * 4 + jj;      // 0..1023
  const int g0 = j, g1 = j + HSZ, g2 = j + 2 * HSZ, g3 = j + 3 * HSZ;

  float m0 = b_ih[g0] + b_hh[g0];
  float m1 = b_ih[g1] + b_hh[g1];
  float m2 = b_ih[g2] + b_hh[g2];
  float m3 = b_ih[g3] + b_hh[g3];
  float c = 0.0f, hp = 0.0f, h = 0.0f, regacc = 0.0f;

  // dh for step 0 is identically zero (h0 == h_prev0 == 0)
  dh0[(size_t)b * HSZ + j] = 0.0f;
  int epoch = 1;
  gbar(flags, epoch); epoch++;

  const float4* __restrict__ wi0 = (const float4*)(w_ih + (size_t)g0 * ISZ);
  const float4* __restrict__ wi1 = (const float4*)(w_ih + (size_t)g1 * ISZ);
  const float4* __restrict__ wi2 = (const float4*)(w_ih + (size_t)g2 * ISZ);
  const float4* __restrict__ wi3 = (const float4*)(w_ih + (size_t)g3 * ISZ);
  const float4* __restrict__ wh0 = (const float4*)(w_hh + (size_t)g0 * HSZ);
  const float4* __restrict__ wh1 = (const float4*)(w_hh + (size_t)g1 * HSZ);
  const float4* __restrict__ wh2 = (const float4*)(w_hh + (size_t)g2 * HSZ);
  const float4* __restrict__ wh3 = (const float4*)(w_hh + (size_t)g3 * HSZ);

  for (int t = 0; t < TSTEPS; t++) {
    float a0 = 0.f, a1 = 0.f, a2 = 0.f, a3 = 0.f;
    {  // x contribution: dx[t,b,:] @ w_ih rows (K=512)
      const float4* __restrict__ xr = (const float4*)(dx + ((size_t)t * BATCH + b) * ISZ);
      #pragma unroll 8
      for (int k = 0; k < ISZ / 4; k++) {
        float4 xv = xr[k]; float4 wv;
        wv = wi0[k]; a0 = fmaf(xv.x, wv.x, fmaf(xv.y, wv.y, fmaf(xv.z, wv.z, fmaf(xv.w, wv.w, a0))));
        wv = wi1[k]; a1 = fmaf(xv.x, wv.x, fmaf(xv.y, wv.y, fmaf(xv.z, wv.z, fmaf(xv.w, wv.w, a1))));
        wv = wi2[k]; a2 = fmaf(xv.x, wv.x, fmaf(xv.y, wv.y, fmaf(xv.z, wv.z, fmaf(xv.w, wv.w, a2))));
        wv = wi3[k]; a3 = fmaf(xv.x, wv.x, fmaf(xv.y, wv.y, fmaf(xv.z, wv.z, fmaf(xv.w, wv.w, a3))));
      }
    }
    {  // h contribution: dh[b,:] @ w_hh rows (K=1024)
      const float* dhb = (t & 1) ? dh1 : dh0;
      const float4* __restrict__ hr = (const float4*)(dhb + (size_t)b * HSZ);
      #pragma unroll 8
      for (int k = 0; k < HSZ / 4; k++) {
        float4 hv = hr[k]; float4 wv;
        wv = wh0[k]; a0 = fmaf(hv.x, wv.x, fmaf(hv.y, wv.y, fmaf(hv.z, wv.z, fmaf(hv.w, wv.w, a0))));
        wv = wh1[k]; a1 = fmaf(hv.x, wv.x, fmaf(hv.y, wv.y, fmaf(hv.z, wv.z, fmaf(hv.w, wv.w, a1))));
        wv = wh2[k]; a2 = fmaf(hv.x, wv.x, fmaf(hv.y, wv.y, fmaf(hv.z, wv.z, fmaf(hv.w, wv.w, a2))));
        wv = wh3[k]; a3 = fmaf(hv.x, wv.x, fmaf(hv.y, wv.y, fmaf(hv.z, wv.z, fmaf(hv.w, wv.w, a3))));
      }
    }
    m0 += a0; m1 += a1; m2 += a2; m3 += a3;

    float pi = qA(m0), pf = qA(m1), pg = qA(m2), po = qA(m3);
    float gi = qN(sigm(pi));
    float gf = qN(sigm(pf));
    float gg = qN(tanhf(pg));
    float go = qN(sigm(po));
    float cn = c * gf + gi * gg;
    c = qA(cn);
    float ct = qN(tanhf(c));
    h = qA(go * ct);
    out[(size_t)t * (BATCH * HSZ) + (size_t)b * HSZ + j] = h;

    if (t < TSTEPS - 1) {  // produce dh for step t+1 (reference computes it at start of t+1)
      float d  = h - hp;
      float da = fabsf(d);
      float dm = (da < TH_QNT) ? 0.0f : d;
      float* nbuf = (t & 1) ? dh0 : dh1;
      nbuf[(size_t)b * HSZ + j] = dm;
      if (da >= TH_RAW) hp = h;
      regacc += fabsf(dm);
    }
    gbar(flags, epoch); epoch++;
  }

  // final state dump (carry after step T-1)
  out[OFF_H  + (size_t)b * HSZ + j] = h;
  out[OFF_HP + (size_t)b * HSZ + j] = hp;
  out[OFF_C  + (size_t)b * HSZ + j] = c;
  out[OFF_M  + (size_t)b * GSZ + g0] = m0;
  out[OFF_M  + (size_t)b * GSZ + g1] = m1;
  out[OFF_M  + (size_t)b * GSZ + g2] = m2;
  out[OFF_M  + (size_t)b * GSZ + g3] = m3;

  // deterministic reg reduction: block tree-reduce -> partials -> block 0
  __shared__ float red[NT];
  red[tid] = regacc;
  __syncthreads();
  for (int s = NT / 2; s > 0; s >>= 1) {
    if (tid < s) red[tid] += red[tid + s];
    __syncthreads();
  }
  if (tid == 0) partials[blockIdx.x] = red[0];
  gbar(flags, epoch); epoch++;
  if (blockIdx.x == 0) {
    red[tid] = partials[tid];  // NT == NB == 256
    __syncthreads();
    for (int s = NT / 2; s > 0; s >>= 1) {
      if (tid < s) red[tid] += red[tid + s];
      __syncthreads();
    }
    if (tid == 0) out[OFF_REG] = red[0];
  }
}

// ---------------------------------------------------------------------------
extern "C" void kernel_launch(void* const* d_in, const int* in_sizes, int n_in,
                              void* d_out, int out_size, void* d_ws, size_t ws_size,
                              hipStream_t stream) {
  const float* x    = (const float*)d_in[0];
  const float* w_ih = (const float*)d_in[1];
  const float* w_hh = (const float*)d_in[2];
  const float* b_ih = (const float*)d_in[3];
  const float* b_hh = (const float*)d_in[4];
  float* out = (float*)d_out;

  const size_t dx_elems = (size_t)TSTEPS * BATCH * ISZ;  // 16,777,216 floats = 64 MiB
  float* dx       = (float*)d_ws;
  float* dh0      = dx + dx_elems;
  float* dh1      = dh0 + (size_t)BATCH * HSZ;
  float* partials = dh1 + (size_t)BATCH * HSZ;
  int*   flags    = (int*)(partials + NB);
  size_t needed = (size_t)((char*)(flags + NB) - (char*)d_ws);
  if (ws_size < needed) return;  // fail validation cleanly rather than corrupt memory

  hipMemsetAsync(flags, 0, NB * sizeof(int), stream);  // barrier flags must start at 0
  xscan_kernel<<<128, 256, 0, stream>>>(x, dx, out + OFF_XPREV);
  scan_kernel<<<NB, NT, 0, stream>>>(dx, w_ih, w_hh, b_ih, b_hh, out,
                                     dh0, dh1, partials, flags);
}

// Round 6
// 99384.100 us; speedup vs baseline: 1.7187x; 1.0199x over previous
//
#include <hip/hip_runtime.h>
#include <hip/hip_fp16.h>
#include <stdint.h>

typedef unsigned short ushort_t;
typedef unsigned int uint_t;
typedef unsigned long long ull_t;

#define TSTEPS 512
#define BATCH  64
#define ISZ    512
#define HSZ    1024
#define GSZ    4096
#define NB     256
#define NT     256

static constexpr size_t OFF_XPREV = (size_t)TSTEPS * BATCH * HSZ;      // 33554432
static constexpr size_t OFF_H     = OFF_XPREV + (size_t)BATCH * 1024;  // x_prev padded to max(I,H)=1024
static constexpr size_t OFF_HP    = OFF_H  + (size_t)BATCH * HSZ;
static constexpr size_t OFF_C     = OFF_HP + (size_t)BATCH * HSZ;
static constexpr size_t OFF_M     = OFF_C  + (size_t)BATCH * HSZ;
static constexpr size_t OFF_REG   = OFF_M  + (size_t)BATCH * GSZ;

#define TH_RAW 0.1f
#define TH_QNT 0.1015625f   // quantize(0.1, Q8.8) = rint(25.6)/256 = 26/256

// Q8.8 fake-quantize: clip(rint(x*256), -32768, 32767)/256  (rintf = RTNE = jnp.round)
__device__ __forceinline__ float qA(float x) {
  float v = rintf(x * 256.0f);
  v = fminf(fmaxf(v, -32768.0f), 32767.0f);
  return v * 0.00390625f;
}
// Q2.8 fake-quantize: clip(rint(x*256), -512, 511)/256
__device__ __forceinline__ float qN(float x) {
  float v = rintf(x * 256.0f);
  v = fminf(fmaxf(v, -512.0f), 511.0f);
  return v * 0.00390625f;
}
__device__ __forceinline__ float sigm(float x) { return 1.0f / (1.0f + expf(-x)); }

// ---------------------------------------------------------------------------
// Phase A: quantize x, sequential x-delta scan (exact fixed-point; independent
// of the recurrence). One thread per (b,i). Writes dx[T,B,I] and x_prev output.
// ---------------------------------------------------------------------------
__global__ __launch_bounds__(256) void xscan_kernel(const float* __restrict__ x,
                                                    float* __restrict__ dx,
                                                    float* __restrict__ out_xprev) {
  const int gid = blockIdx.x * blockDim.x + threadIdx.x;  // 0..32767 == b*512+i
  float xp = 0.0f;
  #pragma unroll 8
  for (int t = 0; t < TSTEPS; t++) {
    float xq = qA(x[(size_t)t * (BATCH * ISZ) + gid]);
    float d  = xq - xp;
    float da = fabsf(d);
    dx[(size_t)t * (BATCH * ISZ) + gid] = (da < TH_QNT) ? 0.0f : d;
    if (da >= TH_RAW) xp = xq;
  }
  const int b = gid >> 9;
  const int i = gid & 511;
  out_xprev[(size_t)b * 1024 + i]       = xp;    // first I columns
  out_xprev[(size_t)b * 1024 + 512 + i] = 0.0f;  // zero pad to max(I,H)
}

// ---------------------------------------------------------------------------
// Flag-array grid barrier, NO cache invalidation:
// arrival = RELEASE store of epoch (s_waitcnt + sc store; orders the
// preceding relaxed dh stores; no buffer_inv). wait = relaxed agent polls.
// NO acquire afterwards: cross-block data (dh) is read via agent-scope
// atomic loads, so cached read-only state (weights/dx) stays valid.
// ---------------------------------------------------------------------------
__device__ __forceinline__ void gbar(int* flags, int e) {
  __syncthreads();
  if (threadIdx.x == 0) {
    __hip_atomic_store(&flags[blockIdx.x], e, __ATOMIC_RELEASE, __HIP_MEMORY_SCOPE_AGENT);
  }
  int ok;
  do {
    int f = __hip_atomic_load(&flags[threadIdx.x], __ATOMIC_RELAXED, __HIP_MEMORY_SCOPE_AGENT);
    ok = __syncthreads_and(f >= e);
    if (!ok) __builtin_amdgcn_s_sleep(1);
  } while (!ok);
  __syncthreads();
}

// ---------------------------------------------------------------------------
// dh batch machinery, COMPILER-VISIBLE loads (fix for round-5 NaN):
// __hip_atomic_load relaxed/agent on u64 -> global_load_dwordx2 with the
// agent-scope sc bits: reads the coherence point (sees remote-XCD writes,
// invalidates nothing), and the compiler inserts exact waitcnts and handles
// spills correctly (the round-5 asm pipeline spilled not-yet-written asm
// output regs -> NaN).  Batch = 16 u64 = 64 fp16; consume ~700 VALU cycles
// >= one L3 latency, so the 1-deep double buffer hides the fetch.
// ---------------------------------------------------------------------------
__device__ __forceinline__ void loadB(ull_t (&L)[16], const ull_t* __restrict__ p) {
  #pragma unroll
  for (int i = 0; i < 16; ++i)
    L[i] = __hip_atomic_load(p + i, __ATOMIC_RELAXED, __HIP_MEMORY_SCOPE_AGENT);
}

__device__ __forceinline__ void consB(const ull_t (&L)[16], int bb,
    const float4* __restrict__ wh0, const float4* __restrict__ wh1,
    const float4* __restrict__ wh2, const float4* __restrict__ wh3,
    float& a0, float& a1, float& a2, float& a3) {
  #pragma unroll
  for (int i = 0; i < 16; ++i) {
    const uint_t lo = (uint_t)L[i];
    const uint_t hi = (uint_t)(L[i] >> 32);
    float h0 = __half2float(__ushort_as_half((ushort_t)(lo & 0xffff)));
    float h1 = __half2float(__ushort_as_half((ushort_t)(lo >> 16)));
    float h2 = __half2float(__ushort_as_half((ushort_t)(hi & 0xffff)));
    float h3 = __half2float(__ushort_as_half((ushort_t)(hi >> 16)));
    const int wi = bb * 16 + i;
    float4 w;
    w = wh0[wi]; a0 = fmaf(h0, w.x, fmaf(h1, w.y, fmaf(h2, w.z, fmaf(h3, w.w, a0))));
    w = wh1[wi]; a1 = fmaf(h0, w.x, fmaf(h1, w.y, fmaf(h2, w.z, fmaf(h3, w.w, a1))));
    w = wh2[wi]; a2 = fmaf(h0, w.x, fmaf(h1, w.y, fmaf(h2, w.z, fmaf(h3, w.w, a2))));
    w = wh3[wi]; a3 = fmaf(h0, w.x, fmaf(h1, w.y, fmaf(h2, w.z, fmaf(h3, w.w, a3))));
  }
}

// ---------------------------------------------------------------------------
// Phase B: persistent scan. 256 blocks x 256 threads = 65536 = B*H sites.
// Thread (b,j) owns c, h_prev, m[4 gates] in registers for all 512 steps.
// Weights/dx: plain cached loads (L1/L2-resident -- never invalidated).
// dh: fp16 ping-pong, relaxed-atomic dword stores, atomic u64 batch reads.
// ---------------------------------------------------------------------------
__global__ __launch_bounds__(NT, 1) void scan_kernel(
    const float* __restrict__ dx, const float* __restrict__ w_ih,
    const float* __restrict__ w_hh, const float* __restrict__ b_ih,
    const float* __restrict__ b_hh, float* __restrict__ out,
    __half* __restrict__ dh16,          // 2 buffers of B*H fp16 (ping-pong)
    float* __restrict__ partials, int* flags) {
  const int tid = threadIdx.x;
  const int jj  = tid & 3;
  const int b   = tid >> 2;                 // 0..63
  const int j   = blockIdx.x * 4 + jj;      // 0..1023
  const int g0 = j, g1 = j + HSZ, g2 = j + 2 * HSZ, g3 = j + 3 * HSZ;
  const size_t DHBUF = (size_t)BATCH * HSZ; // halves per buffer

  float m0 = b_ih[g0] + b_hh[g0];
  float m1 = b_ih[g1] + b_hh[g1];
  float m2 = b_ih[g2] + b_hh[g2];
  float m3 = b_ih[g3] + b_hh[g3];
  float c = 0.0f, hp = 0.0f, h = 0.0f, regacc = 0.0f;

  const float4* __restrict__ wi0 = (const float4*)(w_ih + (size_t)g0 * ISZ);
  const float4* __restrict__ wi1 = (const float4*)(w_ih + (size_t)g1 * ISZ);
  const float4* __restrict__ wi2 = (const float4*)(w_ih + (size_t)g2 * ISZ);
  const float4* __restrict__ wi3 = (const float4*)(w_ih + (size_t)g3 * ISZ);
  const float4* __restrict__ wh0 = (const float4*)(w_hh + (size_t)g0 * HSZ);
  const float4* __restrict__ wh1 = (const float4*)(w_hh + (size_t)g1 * HSZ);
  const float4* __restrict__ wh2 = (const float4*)(w_hh + (size_t)g2 * HSZ);
  const float4* __restrict__ wh3 = (const float4*)(w_hh + (size_t)g3 * HSZ);

  ull_t L0[16], L1[16];
  int epoch = 1;

  for (int t = 0; t < TSTEPS; t++) {
    // read buffer for this step: (t&1); zero-initialized by host memset for t=0
    const ull_t* __restrict__ hrow =
        (const ull_t*)(dh16 + (size_t)(t & 1) * DHBUF + (size_t)b * HSZ);

    loadB(L0, hrow);  // batch 0 in flight during the x-part

    float a0 = 0.f, a1 = 0.f, a2 = 0.f, a3 = 0.f;
    {  // x contribution: dx[t,b,:] @ w_ih rows (K=512), plain cached loads
      const float4* __restrict__ xr = (const float4*)(dx + ((size_t)t * BATCH + b) * ISZ);
      #pragma unroll 8
      for (int k = 0; k < ISZ / 4; k++) {
        float4 xv = xr[k]; float4 wv;
        wv = wi0[k]; a0 = fmaf(xv.x, wv.x, fmaf(xv.y, wv.y, fmaf(xv.z, wv.z, fmaf(xv.w, wv.w, a0))));
        wv = wi1[k]; a1 = fmaf(xv.x, wv.x, fmaf(xv.y, wv.y, fmaf(xv.z, wv.z, fmaf(xv.w, wv.w, a1))));
        wv = wi2[k]; a2 = fmaf(xv.x, wv.x, fmaf(xv.y, wv.y, fmaf(xv.z, wv.z, fmaf(xv.w, wv.w, a2))));
        wv = wi3[k]; a3 = fmaf(xv.x, wv.x, fmaf(xv.y, wv.y, fmaf(xv.z, wv.z, fmaf(xv.w, wv.w, a3))));
      }
    }

    // h contribution: 16 batches of 16 u64 (=64 fp16), double-buffered
    for (int bb = 0; bb < 16; bb += 2) {
      loadB(L1, hrow + (bb + 1) * 16);
      consB(L0, bb, wh0, wh1, wh2, wh3, a0, a1, a2, a3);
      if (bb < 14) loadB(L0, hrow + (bb + 2) * 16);
      consB(L1, bb + 1, wh0, wh1, wh2, wh3, a0, a1, a2, a3);
    }

    m0 += a0; m1 += a1; m2 += a2; m3 += a3;

    float pi = qA(m0), pf = qA(m1), pg = qA(m2), po = qA(m3);
    float gi = qN(sigm(pi));
    float gf = qN(sigm(pf));
    float gg = qN(tanhf(pg));
    float go = qN(sigm(po));
    float cn = c * gf + gi * gg;
    c = qA(cn);
    float ct = qN(tanhf(c));
    h = qA(go * ct);
    out[(size_t)t * (BATCH * HSZ) + (size_t)b * HSZ + j] = h;

    if (t < TSTEPS - 1) {  // produce dh for step t+1 into the other buffer
      float d  = h - hp;
      float da = fabsf(d);
      float dm = (da < TH_QNT) ? 0.0f : d;
      if (da >= TH_RAW) hp = h;
      regacc += fabsf(dm);
      // fp16 is exact for dh (Q8.8 delta, |dh*256| <= 1022)
      ushort_t my = __half_as_ushort(__float2half(dm));
      ushort_t other = (ushort_t)__shfl((int)my, tid ^ 1, 64);
      if ((tid & 1) == 0) {  // even lane owns dword (j, j+1): j even -> low half
        uint_t dw = (uint_t)my | ((uint_t)other << 16);
        uint_t* dhw = (uint_t*)(dh16 + (size_t)((t + 1) & 1) * DHBUF);
        __hip_atomic_store(&dhw[((size_t)b * HSZ + j) >> 1], dw,
                           __ATOMIC_RELAXED, __HIP_MEMORY_SCOPE_AGENT);
      }
    }
    gbar(flags, epoch); epoch++;
  }

  // final state dump (carry after step T-1)
  out[OFF_H  + (size_t)b * HSZ + j] = h;
  out[OFF_HP + (size_t)b * HSZ + j] = hp;
  out[OFF_C  + (size_t)b * HSZ + j] = c;
  out[OFF_M  + (size_t)b * GSZ + g0] = m0;
  out[OFF_M  + (size_t)b * GSZ + g1] = m1;
  out[OFF_M  + (size_t)b * GSZ + g2] = m2;
  out[OFF_M  + (size_t)b * GSZ + g3] = m3;

  // deterministic reg reduction: block tree-reduce -> partials -> block 0
  __shared__ float red[NT];
  red[tid] = regacc;
  __syncthreads();
  for (int s = NT / 2; s > 0; s >>= 1) {
    if (tid < s) red[tid] += red[tid + s];
    __syncthreads();
  }
  if (tid == 0)
    __hip_atomic_store(&partials[blockIdx.x], red[0], __ATOMIC_RELAXED, __HIP_MEMORY_SCOPE_AGENT);
  gbar(flags, epoch); epoch++;
  if (blockIdx.x == 0) {
    red[tid] = __hip_atomic_load(&partials[tid], __ATOMIC_RELAXED, __HIP_MEMORY_SCOPE_AGENT);
    __syncthreads();
    for (int s = NT / 2; s > 0; s >>= 1) {
      if (tid < s) red[tid] += red[tid + s];
      __syncthreads();
    }
    if (tid == 0) out[OFF_REG] = red[0];
  }
}

// ---------------------------------------------------------------------------
extern "C" void kernel_launch(void* const* d_in, const int* in_sizes, int n_in,
                              void* d_out, int out_size, void* d_ws, size_t ws_size,
                              hipStream_t stream) {
  const float* x    = (const float*)d_in[0];
  const float* w_ih = (const float*)d_in[1];
  const float* w_hh = (const float*)d_in[2];
  const float* b_ih = (const float*)d_in[3];
  const float* b_hh = (const float*)d_in[4];
  float* out = (float*)d_out;

  const size_t dx_elems = (size_t)TSTEPS * BATCH * ISZ;  // 16,777,216 floats = 64 MiB
  float*  dx       = (float*)d_ws;
  __half* dh16     = (__half*)(dx + dx_elems);           // 2 x 64*1024 fp16 = 256 KiB
  float*  partials = (float*)(dh16 + 2 * (size_t)BATCH * HSZ);
  int*    flags    = (int*)(partials + NB);
  size_t needed = (size_t)((char*)(flags + NB) - (char*)d_ws);
  if (ws_size < needed) return;  // fail validation cleanly rather than corrupt memory

  // dh buffers must be zero (fp16 0x0000) and flags 0 before the scan
  (void)hipMemsetAsync(dh16, 0, 2 * (size_t)BATCH * HSZ * sizeof(__half), stream);
  (void)hipMemsetAsync(flags, 0, NB * sizeof(int), stream);
  xscan_kernel<<<128, 256, 0, stream>>>(x, dx, out + OFF_XPREV);
  scan_kernel<<<NB, NT, 0, stream>>>(dx, w_ih, w_hh, b_ih, b_hh, out,
                                     dh16, partials, flags);
}

// Round 7
// 96501.947 us; speedup vs baseline: 1.7700x; 1.0299x over previous
//
#include <hip/hip_runtime.h>
#include <hip/hip_fp16.h>
#include <stdint.h>

typedef unsigned short ushort_t;
typedef unsigned int uint_t;
typedef unsigned long long ull_t;

#define TSTEPS 512
#define BATCH  64
#define ISZ    512
#define HSZ    1024
#define GSZ    4096
#define NB     256
#define NT     256

static constexpr size_t OFF_XPREV = (size_t)TSTEPS * BATCH * HSZ;      // 33554432
static constexpr size_t OFF_H     = OFF_XPREV + (size_t)BATCH * 1024;  // x_prev padded to max(I,H)=1024
static constexpr size_t OFF_HP    = OFF_H  + (size_t)BATCH * HSZ;
static constexpr size_t OFF_C     = OFF_HP + (size_t)BATCH * HSZ;
static constexpr size_t OFF_M     = OFF_C  + (size_t)BATCH * HSZ;
static constexpr size_t OFF_REG   = OFF_M  + (size_t)BATCH * GSZ;

#define TH_RAW 0.1f
#define TH_QNT 0.1015625f   // quantize(0.1, Q8.8) = rint(25.6)/256 = 26/256

// Q8.8 fake-quantize: clip(rint(x*256), -32768, 32767)/256  (rintf = RTNE = jnp.round)
__device__ __forceinline__ float qA(float x) {
  float v = rintf(x * 256.0f);
  v = fminf(fmaxf(v, -32768.0f), 32767.0f);
  return v * 0.00390625f;
}
// Q2.8 fake-quantize: clip(rint(x*256), -512, 511)/256
__device__ __forceinline__ float qN(float x) {
  float v = rintf(x * 256.0f);
  v = fminf(fmaxf(v, -512.0f), 511.0f);
  return v * 0.00390625f;
}
__device__ __forceinline__ float sigm(float x) { return 1.0f / (1.0f + expf(-x)); }

// ---------------------------------------------------------------------------
// Phase A: quantize x, sequential x-delta scan (exact fixed-point; independent
// of the recurrence). One thread per (b,i). Writes dx[T,B,I] and x_prev output.
// ---------------------------------------------------------------------------
__global__ __launch_bounds__(256) void xscan_kernel(const float* __restrict__ x,
                                                    float* __restrict__ dx,
                                                    float* __restrict__ out_xprev) {
  const int gid = blockIdx.x * blockDim.x + threadIdx.x;  // 0..32767 == b*512+i
  float xp = 0.0f;
  #pragma unroll 8
  for (int t = 0; t < TSTEPS; t++) {
    float xq = qA(x[(size_t)t * (BATCH * ISZ) + gid]);
    float d  = xq - xp;
    float da = fabsf(d);
    dx[(size_t)t * (BATCH * ISZ) + gid] = (da < TH_QNT) ? 0.0f : d;
    if (da >= TH_RAW) xp = xq;
  }
  const int b = gid >> 9;
  const int i = gid & 511;
  out_xprev[(size_t)b * 1024 + i]       = xp;    // first I columns
  out_xprev[(size_t)b * 1024 + 512 + i] = 0.0f;  // zero pad to max(I,H)
}

// ---------------------------------------------------------------------------
// Flag-array grid barrier with NO release fence (round-7 change):
// an agent-scope RELEASE on gfx950 lowers to buffer_wbl2 (full L2 dirty
// writeback walk) -- issued per block per step, this is the ~175us/step
// invariant cost of rounds 1/3/6.  It is semantically unnecessary here:
// the dh stores are relaxed sc0sc1 write-THROUGH ops that land at the
// coherence point; s_waitcnt vmcnt(0) (explicit + the one __syncthreads
// emits) guarantees they are ACK'd before the flag store issues.  Arrival
// is therefore: drain vmcnt -> RELAXED agent store.  Zero cache-maintenance
// instructions remain in the step loop.
// ---------------------------------------------------------------------------
__device__ __forceinline__ void gbar(int* flags, int e) {
  asm volatile("s_waitcnt vmcnt(0)" ::: "memory");  // all my stores ACK'd at coherence point
  __syncthreads();                                  // all waves of the block drained
  if (threadIdx.x == 0) {
    __hip_atomic_store(&flags[blockIdx.x], e, __ATOMIC_RELAXED, __HIP_MEMORY_SCOPE_AGENT);
  }
  int ok;
  do {
    int f = __hip_atomic_load(&flags[threadIdx.x], __ATOMIC_RELAXED, __HIP_MEMORY_SCOPE_AGENT);
    ok = __syncthreads_and(f >= e);
    if (!ok) __builtin_amdgcn_s_sleep(1);
  } while (!ok);
  __syncthreads();
}

// ---------------------------------------------------------------------------
// dh batch machinery, compiler-visible agent-scope loads (validated round 6):
// __hip_atomic_load relaxed/agent on u64 -> dwordx2 with sc bits: reads the
// coherence point (sees remote-XCD writes, invalidates nothing); compiler
// inserts exact waitcnts and spills correctly.
// ---------------------------------------------------------------------------
__device__ __forceinline__ void loadB(ull_t (&L)[16], const ull_t* __restrict__ p) {
  #pragma unroll
  for (int i = 0; i < 16; ++i)
    L[i] = __hip_atomic_load(p + i, __ATOMIC_RELAXED, __HIP_MEMORY_SCOPE_AGENT);
}

__device__ __forceinline__ void consB(const ull_t (&L)[16], int bb,
    const float4* __restrict__ wh0, const float4* __restrict__ wh1,
    const float4* __restrict__ wh2, const float4* __restrict__ wh3,
    float& a0, float& a1, float& a2, float& a3) {
  #pragma unroll
  for (int i = 0; i < 16; ++i) {
    const uint_t lo = (uint_t)L[i];
    const uint_t hi = (uint_t)(L[i] >> 32);
    float h0 = __half2float(__ushort_as_half((ushort_t)(lo & 0xffff)));
    float h1 = __half2float(__ushort_as_half((ushort_t)(lo >> 16)));
    float h2 = __half2float(__ushort_as_half((ushort_t)(hi & 0xffff)));
    float h3 = __half2float(__ushort_as_half((ushort_t)(hi >> 16)));
    const int wi = bb * 16 + i;
    float4 w;
    w = wh0[wi]; a0 = fmaf(h0, w.x, fmaf(h1, w.y, fmaf(h2, w.z, fmaf(h3, w.w, a0))));
    w = wh1[wi]; a1 = fmaf(h0, w.x, fmaf(h1, w.y, fmaf(h2, w.z, fmaf(h3, w.w, a1))));
    w = wh2[wi]; a2 = fmaf(h0, w.x, fmaf(h1, w.y, fmaf(h2, w.z, fmaf(h3, w.w, a2))));
    w = wh3[wi]; a3 = fmaf(h0, w.x, fmaf(h1, w.y, fmaf(h2, w.z, fmaf(h3, w.w, a3))));
  }
}

// ---------------------------------------------------------------------------
// Phase B: persistent scan. 256 blocks x 256 threads = 65536 = B*H sites.
// Thread (b,j) owns c, h_prev, m[4 gates] in registers for all 512 steps.
// Weights/dx: plain cached loads (L1/L2-resident -- never invalidated).
// dh: fp16 ping-pong, relaxed-atomic dword stores, atomic u64 batch reads.
// ---------------------------------------------------------------------------
__global__ __launch_bounds__(NT, 1) void scan_kernel(
    const float* __restrict__ dx, const float* __restrict__ w_ih,
    const float* __restrict__ w_hh, const float* __restrict__ b_ih,
    const float* __restrict__ b_hh, float* __restrict__ out,
    __half* __restrict__ dh16,          // 2 buffers of B*H fp16 (ping-pong)
    float* __restrict__ partials, int* flags) {
  const int tid = threadIdx.x;
  const int jj  = tid & 3;
  const int b   = tid >> 2;                 // 0..63
  const int j   = blockIdx.x * 4 + jj;      // 0..1023
  const int g0 = j, g1 = j + HSZ, g2 = j + 2 * HSZ, g3 = j + 3 * HSZ;
  const size_t DHBUF = (size_t)BATCH * HSZ; // halves per buffer

  float m0 = b_ih[g0] + b_hh[g0];
  float m1 = b_ih[g1] + b_hh[g1];
  float m2 = b_ih[g2] + b_hh[g2];
  float m3 = b_ih[g3] + b_hh[g3];
  float c = 0.0f, hp = 0.0f, h = 0.0f, regacc = 0.0f;

  const float4* __restrict__ wi0 = (const float4*)(w_ih + (size_t)g0 * ISZ);
  const float4* __restrict__ wi1 = (const float4*)(w_ih + (size_t)g1 * ISZ);
  const float4* __restrict__ wi2 = (const float4*)(w_ih + (size_t)g2 * ISZ);
  const float4* __restrict__ wi3 = (const float4*)(w_ih + (size_t)g3 * ISZ);
  const float4* __restrict__ wh0 = (const float4*)(w_hh + (size_t)g0 * HSZ);
  const float4* __restrict__ wh1 = (const float4*)(w_hh + (size_t)g1 * HSZ);
  const float4* __restrict__ wh2 = (const float4*)(w_hh + (size_t)g2 * HSZ);
  const float4* __restrict__ wh3 = (const float4*)(w_hh + (size_t)g3 * HSZ);

  ull_t L0[16], L1[16];
  int epoch = 1;

  for (int t = 0; t < TSTEPS; t++) {
    // read buffer for this step: (t&1); zero-initialized by host memset for t=0
    const ull_t* __restrict__ hrow =
        (const ull_t*)(dh16 + (size_t)(t & 1) * DHBUF + (size_t)b * HSZ);

    loadB(L0, hrow);  // batch 0 in flight during the x-part

    float a0 = 0.f, a1 = 0.f, a2 = 0.f, a3 = 0.f;
    {  // x contribution: dx[t,b,:] @ w_ih rows (K=512), plain cached loads
      const float4* __restrict__ xr = (const float4*)(dx + ((size_t)t * BATCH + b) * ISZ);
      #pragma unroll 8
      for (int k = 0; k < ISZ / 4; k++) {
        float4 xv = xr[k]; float4 wv;
        wv = wi0[k]; a0 = fmaf(xv.x, wv.x, fmaf(xv.y, wv.y, fmaf(xv.z, wv.z, fmaf(xv.w, wv.w, a0))));
        wv = wi1[k]; a1 = fmaf(xv.x, wv.x, fmaf(xv.y, wv.y, fmaf(xv.z, wv.z, fmaf(xv.w, wv.w, a1))));
        wv = wi2[k]; a2 = fmaf(xv.x, wv.x, fmaf(xv.y, wv.y, fmaf(xv.z, wv.z, fmaf(xv.w, wv.w, a2))));
        wv = wi3[k]; a3 = fmaf(xv.x, wv.x, fmaf(xv.y, wv.y, fmaf(xv.z, wv.z, fmaf(xv.w, wv.w, a3))));
      }
    }

    // h contribution: 16 batches of 16 u64 (=64 fp16), double-buffered
    for (int bb = 0; bb < 16; bb += 2) {
      loadB(L1, hrow + (bb + 1) * 16);
      consB(L0, bb, wh0, wh1, wh2, wh3, a0, a1, a2, a3);
      if (bb < 14) loadB(L0, hrow + (bb + 2) * 16);
      consB(L1, bb + 1, wh0, wh1, wh2, wh3, a0, a1, a2, a3);
    }

    m0 += a0; m1 += a1; m2 += a2; m3 += a3;

    float pi = qA(m0), pf = qA(m1), pg = qA(m2), po = qA(m3);
    float gi = qN(sigm(pi));
    float gf = qN(sigm(pf));
    float gg = qN(tanhf(pg));
    float go = qN(sigm(po));
    float cn = c * gf + gi * gg;
    c = qA(cn);
    float ct = qN(tanhf(c));
    h = qA(go * ct);
    out[(size_t)t * (BATCH * HSZ) + (size_t)b * HSZ + j] = h;

    if (t < TSTEPS - 1) {  // produce dh for step t+1 into the other buffer
      float d  = h - hp;
      float da = fabsf(d);
      float dm = (da < TH_QNT) ? 0.0f : d;
      if (da >= TH_RAW) hp = h;
      regacc += fabsf(dm);
      // fp16 is exact for dh (Q8.8 delta, |dh*256| <= 1022)
      ushort_t my = __half_as_ushort(__float2half(dm));
      ushort_t other = (ushort_t)__shfl((int)my, tid ^ 1, 64);
      if ((tid & 1) == 0) {  // even lane owns dword (j, j+1): j even -> low half
        uint_t dw = (uint_t)my | ((uint_t)other << 16);
        uint_t* dhw = (uint_t*)(dh16 + (size_t)((t + 1) & 1) * DHBUF);
        __hip_atomic_store(&dhw[((size_t)b * HSZ + j) >> 1], dw,
                           __ATOMIC_RELAXED, __HIP_MEMORY_SCOPE_AGENT);
      }
    }
    gbar(flags, epoch); epoch++;
  }

  // final state dump (carry after step T-1)
  out[OFF_H  + (size_t)b * HSZ + j] = h;
  out[OFF_HP + (size_t)b * HSZ + j] = hp;
  out[OFF_C  + (size_t)b * HSZ + j] = c;
  out[OFF_M  + (size_t)b * GSZ + g0] = m0;
  out[OFF_M  + (size_t)b * GSZ + g1] = m1;
  out[OFF_M  + (size_t)b * GSZ + g2] = m2;
  out[OFF_M  + (size_t)b * GSZ + g3] = m3;

  // deterministic reg reduction: block tree-reduce -> partials -> block 0
  __shared__ float red[NT];
  red[tid] = regacc;
  __syncthreads();
  for (int s = NT / 2; s > 0; s >>= 1) {
    if (tid < s) red[tid] += red[tid + s];
    __syncthreads();
  }
  if (tid == 0)
    __hip_atomic_store(&partials[blockIdx.x], red[0], __ATOMIC_RELAXED, __HIP_MEMORY_SCOPE_AGENT);
  gbar(flags, epoch); epoch++;
  if (blockIdx.x == 0) {
    red[tid] = __hip_atomic_load(&partials[tid], __ATOMIC_RELAXED, __HIP_MEMORY_SCOPE_AGENT);
    __syncthreads();
    for (int s = NT / 2; s > 0; s >>= 1) {
      if (tid < s) red[tid] += red[tid + s];
      __syncthreads();
    }
    if (tid == 0) out[OFF_REG] = red[0];
  }
}

// ---------------------------------------------------------------------------
extern "C" void kernel_launch(void* const* d_in, const int* in_sizes, int n_in,
                              void* d_out, int out_size, void* d_ws, size_t ws_size,
                              hipStream_t stream) {
  const float* x    = (const float*)d_in[0];
  const float* w_ih = (const float*)d_in[1];
  const float* w_hh = (const float*)d_in[2];
  const float* b_ih = (const float*)d_in[3];
  const float* b_hh = (const float*)d_in[4];
  float* out = (float*)d_out;

  const size_t dx_elems = (size_t)TSTEPS * BATCH * ISZ;  // 16,777,216 floats = 64 MiB
  float*  dx       = (float*)d_ws;
  __half* dh16     = (__half*)(dx + dx_elems);           // 2 x 64*1024 fp16 = 256 KiB
  float*  partials = (float*)(dh16 + 2 * (size_t)BATCH * HSZ);
  int*    flags    = (int*)(partials + NB);
  size_t needed = (size_t)((char*)(flags + NB) - (char*)d_ws);
  if (ws_size < needed) return;  // fail validation cleanly rather than corrupt memory

  // dh buffers must be zero (fp16 0x0000) and flags 0 before the scan
  (void)hipMemsetAsync(dh16, 0, 2 * (size_t)BATCH * HSZ * sizeof(__half), stream);
  (void)hipMemsetAsync(flags, 0, NB * sizeof(int), stream);
  xscan_kernel<<<128, 256, 0, stream>>>(x, dx, out + OFF_XPREV);
  scan_kernel<<<NB, NT, 0, stream>>>(dx, w_ih, w_hh, b_ih, b_hh, out,
                                     dh16, partials, flags);
}

// Round 8
// 89770.020 us; speedup vs baseline: 1.9027x; 1.0750x over previous
//
#include <hip/hip_runtime.h>
#include <hip/hip_fp16.h>
#include <stdint.h>

typedef unsigned short ushort_t;
typedef unsigned int uint_t;
typedef unsigned long long ull_t;

#define TSTEPS 512
#define BATCH  64
#define ISZ    512
#define HSZ    1024
#define GSZ    4096
#define NB     256
#define NT     256
#define PITCH  1032   // halves per LDS row (2064 B) -- breaks the 2KB bank alias (2-way = free)
#define SLAB   (16 * PITCH)

static constexpr size_t OFF_XPREV = (size_t)TSTEPS * BATCH * HSZ;      // 33554432
static constexpr size_t OFF_H     = OFF_XPREV + (size_t)BATCH * 1024;  // x_prev padded to max(I,H)=1024
static constexpr size_t OFF_HP    = OFF_H  + (size_t)BATCH * HSZ;
static constexpr size_t OFF_C     = OFF_HP + (size_t)BATCH * HSZ;
static constexpr size_t OFF_M     = OFF_C  + (size_t)BATCH * HSZ;
static constexpr size_t OFF_REG   = OFF_M  + (size_t)BATCH * GSZ;

#define TH_RAW 0.1f
#define TH_QNT 0.1015625f   // quantize(0.1, Q8.8) = rint(25.6)/256 = 26/256

// Q8.8 fake-quantize: clip(rint(x*256), -32768, 32767)/256  (rintf = RTNE = jnp.round)
__device__ __forceinline__ float qA(float x) {
  float v = rintf(x * 256.0f);
  v = fminf(fmaxf(v, -32768.0f), 32767.0f);
  return v * 0.00390625f;
}
// Q2.8 fake-quantize: clip(rint(x*256), -512, 511)/256
__device__ __forceinline__ float qN(float x) {
  float v = rintf(x * 256.0f);
  v = fminf(fmaxf(v, -512.0f), 511.0f);
  return v * 0.00390625f;
}
__device__ __forceinline__ float sigm(float x) { return 1.0f / (1.0f + expf(-x)); }

// ---------------------------------------------------------------------------
// Phase A: quantize x, sequential x-delta scan (exact fixed-point; independent
// of the recurrence). One thread per (b,i). Writes dx[T,B,I] and x_prev output.
// ---------------------------------------------------------------------------
__global__ __launch_bounds__(256) void xscan_kernel(const float* __restrict__ x,
                                                    float* __restrict__ dx,
                                                    float* __restrict__ out_xprev) {
  const int gid = blockIdx.x * blockDim.x + threadIdx.x;  // 0..32767 == b*512+i
  float xp = 0.0f;
  #pragma unroll 8
  for (int t = 0; t < TSTEPS; t++) {
    float xq = qA(x[(size_t)t * (BATCH * ISZ) + gid]);
    float d  = xq - xp;
    float da = fabsf(d);
    dx[(size_t)t * (BATCH * ISZ) + gid] = (da < TH_QNT) ? 0.0f : d;
    if (da >= TH_RAW) xp = xq;
  }
  const int b = gid >> 9;
  const int i = gid & 511;
  out_xprev[(size_t)b * 1024 + i]       = xp;    // first I columns
  out_xprev[(size_t)b * 1024 + 512 + i] = 0.0f;  // zero pad to max(I,H)
}

// ---------------------------------------------------------------------------
// Grid barrier (validated r7 semantics): vmcnt drain -> RELAXED flag store;
// wave 0 polls all 256 flags via paired u64 relaxed agent loads (16 lines
// per block per poll round instead of 4x that when all waves polled).
// No release, no acquire, no cache maintenance anywhere in the loop.
// ---------------------------------------------------------------------------
__device__ __forceinline__ void gbar(int* flags, int e) {
  asm volatile("s_waitcnt vmcnt(0)" ::: "memory");  // my dh stores ACK'd at coherence point
  __syncthreads();                                  // whole block drained
  if (threadIdx.x == 0) {
    __hip_atomic_store(&flags[blockIdx.x], e, __ATOMIC_RELAXED, __HIP_MEMORY_SCOPE_AGENT);
  }
  if (threadIdx.x < 64) {
    const ull_t* f64 = (const ull_t*)flags;
    const int l = threadIdx.x;
    bool done;
    do {
      ull_t a = __hip_atomic_load(f64 + l,      __ATOMIC_RELAXED, __HIP_MEMORY_SCOPE_AGENT);
      ull_t c = __hip_atomic_load(f64 + 64 + l, __ATOMIC_RELAXED, __HIP_MEMORY_SCOPE_AGENT);
      bool ok = ((int)a >= e) & ((int)(a >> 32) >= e) &
                ((int)c >= e) & ((int)(c >> 32) >= e);
      done = __all(ok);
      if (!done) __builtin_amdgcn_s_sleep(2);
    } while (!done);
  }
  __syncthreads();  // waves 1-3 wait for wave 0's poll to finish
}

// ---------------------------------------------------------------------------
// Phase B: persistent scan. 256 blocks x 256 threads = 65536 = B*H sites.
// Thread (b,j) owns c, h_prev, m[4 gates] in registers for all 512 steps.
//
// ROUND-8 CHANGE (the r1..r7 invariant): previously every wave re-fetched dh
// from the coherence point with 16 distinct 64B lines per load instr (8B used
// each, no caching) -> ~4.2M coherence transactions/step chip-wide ~= the
// ~185us/step invariant. Now each wave COALESCE-stages its 16 dh rows (32KB)
// into LDS once per step (512B = 8 full lines per instr), and the dot reads
// LDS. 8x fewer transactions, pipelined; LDS reads broadcast across the
// jj-duplicated lanes. Weights/dx stay plain cached loads (never invalidated).
// ---------------------------------------------------------------------------
__global__ __launch_bounds__(NT, 1) void scan_kernel(
    const float* __restrict__ dx, const float* __restrict__ w_ih,
    const float* __restrict__ w_hh, const float* __restrict__ b_ih,
    const float* __restrict__ b_hh, float* __restrict__ out,
    __half* __restrict__ dh16,          // 2 buffers of B*H fp16 (ping-pong)
    float* __restrict__ partials, int* flags) {
  __shared__ __align__(16) __half dhs[4 * SLAB];   // 132096 B (gfx950: 160KB LDS)
  __shared__ float red[NT];

  const int tid  = threadIdx.x;
  const int wid  = tid >> 6;                // wave 0..3
  const int lane = tid & 63;
  const int jj   = tid & 3;
  const int b    = tid >> 2;                // 0..63 (wave w owns b in [16w,16w+15])
  const int lb   = b & 15;                  // local dh row within the wave's slab
  const int j    = blockIdx.x * 4 + jj;     // 0..1023
  const int g0 = j, g1 = j + HSZ, g2 = j + 2 * HSZ, g3 = j + 3 * HSZ;
  const size_t DHBUF = (size_t)BATCH * HSZ; // halves per ping-pong buffer

  float m0 = b_ih[g0] + b_hh[g0];
  float m1 = b_ih[g1] + b_hh[g1];
  float m2 = b_ih[g2] + b_hh[g2];
  float m3 = b_ih[g3] + b_hh[g3];
  float c = 0.0f, hp = 0.0f, h = 0.0f, regacc = 0.0f;

  const float4* __restrict__ wi0 = (const float4*)(w_ih + (size_t)g0 * ISZ);
  const float4* __restrict__ wi1 = (const float4*)(w_ih + (size_t)g1 * ISZ);
  const float4* __restrict__ wi2 = (const float4*)(w_ih + (size_t)g2 * ISZ);
  const float4* __restrict__ wi3 = (const float4*)(w_ih + (size_t)g3 * ISZ);
  const float4* __restrict__ wh0 = (const float4*)(w_hh + (size_t)g0 * HSZ);
  const float4* __restrict__ wh1 = (const float4*)(w_hh + (size_t)g1 * HSZ);
  const float4* __restrict__ wh2 = (const float4*)(w_hh + (size_t)g2 * HSZ);
  const float4* __restrict__ wh3 = (const float4*)(w_hh + (size_t)g3 * HSZ);

  __half* slab = dhs + wid * SLAB;
  const __half* lrow = slab + lb * PITCH;
  int epoch = 1;

  for (int t = 0; t < TSTEPS; t++) {
    // ---- stage this wave's 16 dh rows (32KB) into LDS, coalesced ----------
    // src: contiguous 4096 u64 = rows 16*wid .. 16*wid+15 of dh[t&1]
    const ull_t* __restrict__ src =
        (const ull_t*)(dh16 + (size_t)(t & 1) * DHBUF) + (size_t)wid * 4096;
    #pragma unroll
    for (int r4 = 0; r4 < 16; r4 += 4) {
      ull_t v[16];
      #pragma unroll
      for (int rr = 0; rr < 4; ++rr)
        #pragma unroll
        for (int i = 0; i < 4; ++i)
          v[rr * 4 + i] = __hip_atomic_load(src + (r4 + rr) * 256 + i * 64 + lane,
                                            __ATOMIC_RELAXED, __HIP_MEMORY_SCOPE_AGENT);
      #pragma unroll
      for (int rr = 0; rr < 4; ++rr)
        #pragma unroll
        for (int i = 0; i < 4; ++i)
          *(ull_t*)(slab + (r4 + rr) * PITCH + (i * 64 + lane) * 4) = v[rr * 4 + i];
    }
    // wave-local: each wave consumes only its own slab; compiler inserts the
    // lgkmcnt waits between ds_write and the ds_reads below. No __syncthreads.

    float a0 = 0.f, a1 = 0.f, a2 = 0.f, a3 = 0.f;
    {  // x contribution: dx[t,b,:] @ w_ih rows (K=512), plain cached loads
      const float4* __restrict__ xr = (const float4*)(dx + ((size_t)t * BATCH + b) * ISZ);
      #pragma unroll 8
      for (int k = 0; k < ISZ / 4; k++) {
        float4 xv = xr[k]; float4 wv;
        wv = wi0[k]; a0 = fmaf(xv.x, wv.x, fmaf(xv.y, wv.y, fmaf(xv.z, wv.z, fmaf(xv.w, wv.w, a0))));
        wv = wi1[k]; a1 = fmaf(xv.x, wv.x, fmaf(xv.y, wv.y, fmaf(xv.z, wv.z, fmaf(xv.w, wv.w, a1))));
        wv = wi2[k]; a2 = fmaf(xv.x, wv.x, fmaf(xv.y, wv.y, fmaf(xv.z, wv.z, fmaf(xv.w, wv.w, a2))));
        wv = wi3[k]; a3 = fmaf(xv.x, wv.x, fmaf(xv.y, wv.y, fmaf(xv.z, wv.z, fmaf(xv.w, wv.w, a3))));
      }
    }

    {  // h contribution: dh row (from LDS) @ w_hh rows (K=1024)
      #pragma unroll 4
      for (int i = 0; i < 128; ++i) {
        uint4 u = *(const uint4*)(lrow + i * 8);   // ds_read_b128: 8 halves
        float h0 = __half2float(__ushort_as_half((ushort_t)(u.x & 0xffff)));
        float h1 = __half2float(__ushort_as_half((ushort_t)(u.x >> 16)));
        float h2 = __half2float(__ushort_as_half((ushort_t)(u.y & 0xffff)));
        float h3 = __half2float(__ushort_as_half((ushort_t)(u.y >> 16)));
        float h4 = __half2float(__ushort_as_half((ushort_t)(u.z & 0xffff)));
        float h5 = __half2float(__ushort_as_half((ushort_t)(u.z >> 16)));
        float h6 = __half2float(__ushort_as_half((ushort_t)(u.w & 0xffff)));
        float h7 = __half2float(__ushort_as_half((ushort_t)(u.w >> 16)));
        const int wi = i * 2;
        float4 w;
        w = wh0[wi];     a0 = fmaf(h0, w.x, fmaf(h1, w.y, fmaf(h2, w.z, fmaf(h3, w.w, a0))));
        w = wh0[wi + 1]; a0 = fmaf(h4, w.x, fmaf(h5, w.y, fmaf(h6, w.z, fmaf(h7, w.w, a0))));
        w = wh1[wi];     a1 = fmaf(h0, w.x, fmaf(h1, w.y, fmaf(h2, w.z, fmaf(h3, w.w, a1))));
        w = wh1[wi + 1]; a1 = fmaf(h4, w.x, fmaf(h5, w.y, fmaf(h6, w.z, fmaf(h7, w.w, a1))));
        w = wh2[wi];     a2 = fmaf(h0, w.x, fmaf(h1, w.y, fmaf(h2, w.z, fmaf(h3, w.w, a2))));
        w = wh2[wi + 1]; a2 = fmaf(h4, w.x, fmaf(h5, w.y, fmaf(h6, w.z, fmaf(h7, w.w, a2))));
        w = wh3[wi];     a3 = fmaf(h0, w.x, fmaf(h1, w.y, fmaf(h2, w.z, fmaf(h3, w.w, a3))));
        w = wh3[wi + 1]; a3 = fmaf(h4, w.x, fmaf(h5, w.y, fmaf(h6, w.z, fmaf(h7, w.w, a3))));
      }
    }

    m0 += a0; m1 += a1; m2 += a2; m3 += a3;

    float pi = qA(m0), pf = qA(m1), pg = qA(m2), po = qA(m3);
    float gi = qN(sigm(pi));
    float gf = qN(sigm(pf));
    float gg = qN(tanhf(pg));
    float go = qN(sigm(po));
    float cn = c * gf + gi * gg;
    c = qA(cn);
    float ct = qN(tanhf(c));
    h = qA(go * ct);
    out[(size_t)t * (BATCH * HSZ) + (size_t)b * HSZ + j] = h;

    if (t < TSTEPS - 1) {  // produce dh for step t+1 into the other buffer
      float d  = h - hp;
      float da = fabsf(d);
      float dm = (da < TH_QNT) ? 0.0f : d;
      if (da >= TH_RAW) hp = h;
      regacc += fabsf(dm);
      // fp16 is exact for dh (Q8.8 delta, |dh*256| <= 1022)
      ushort_t my = __half_as_ushort(__float2half(dm));
      ushort_t other = (ushort_t)__shfl((int)my, tid ^ 1, 64);
      if ((tid & 1) == 0) {  // even lane owns dword (j, j+1)
        uint_t dw = (uint_t)my | ((uint_t)other << 16);
        uint_t* dhw = (uint_t*)(dh16 + (size_t)((t + 1) & 1) * DHBUF);
        __hip_atomic_store(&dhw[((size_t)b * HSZ + j) >> 1], dw,
                           __ATOMIC_RELAXED, __HIP_MEMORY_SCOPE_AGENT);
      }
    }
    gbar(flags, epoch); epoch++;
  }

  // final state dump (carry after step T-1)
  out[OFF_H  + (size_t)b * HSZ + j] = h;
  out[OFF_HP + (size_t)b * HSZ + j] = hp;
  out[OFF_C  + (size_t)b * HSZ + j] = c;
  out[OFF_M  + (size_t)b * GSZ + g0] = m0;
  out[OFF_M  + (size_t)b * GSZ + g1] = m1;
  out[OFF_M  + (size_t)b * GSZ + g2] = m2;
  out[OFF_M  + (size_t)b * GSZ + g3] = m3;

  // deterministic reg reduction: block tree-reduce -> partials -> block 0
  red[tid] = regacc;
  __syncthreads();
  for (int s = NT / 2; s > 0; s >>= 1) {
    if (tid < s) red[tid] += red[tid + s];
    __syncthreads();
  }
  if (tid == 0)
    __hip_atomic_store(&partials[blockIdx.x], red[0], __ATOMIC_RELAXED, __HIP_MEMORY_SCOPE_AGENT);
  gbar(flags, epoch); epoch++;
  if (blockIdx.x == 0) {
    red[tid] = __hip_atomic_load(&partials[tid], __ATOMIC_RELAXED, __HIP_MEMORY_SCOPE_AGENT);
    __syncthreads();
    for (int s = NT / 2; s > 0; s >>= 1) {
      if (tid < s) red[tid] += red[tid + s];
      __syncthreads();
    }
    if (tid == 0) out[OFF_REG] = red[0];
  }
}

// ---------------------------------------------------------------------------
extern "C" void kernel_launch(void* const* d_in, const int* in_sizes, int n_in,
                              void* d_out, int out_size, void* d_ws, size_t ws_size,
                              hipStream_t stream) {
  const float* x    = (const float*)d_in[0];
  const float* w_ih = (const float*)d_in[1];
  const float* w_hh = (const float*)d_in[2];
  const float* b_ih = (const float*)d_in[3];
  const float* b_hh = (const float*)d_in[4];
  float* out = (float*)d_out;

  const size_t dx_elems = (size_t)TSTEPS * BATCH * ISZ;  // 16,777,216 floats = 64 MiB
  float*  dx       = (float*)d_ws;
  __half* dh16     = (__half*)(dx + dx_elems);           // 2 x 64*1024 fp16 = 256 KiB
  float*  partials = (float*)(dh16 + 2 * (size_t)BATCH * HSZ);
  int*    flags    = (int*)(partials + NB);
  size_t needed = (size_t)((char*)(flags + NB) - (char*)d_ws);
  if (ws_size < needed) return;  // fail validation cleanly rather than corrupt memory

  // dh buffers must be zero (fp16 0x0000) and flags 0 before the scan
  (void)hipMemsetAsync(dh16, 0, 2 * (size_t)BATCH * HSZ * sizeof(__half), stream);
  (void)hipMemsetAsync(flags, 0, NB * sizeof(int), stream);
  xscan_kernel<<<128, 256, 0, stream>>>(x, dx, out + OFF_XPREV);
  scan_kernel<<<NB, NT, 0, stream>>>(dx, w_ih, w_hh, b_ih, b_hh, out,
                                     dh16, partials, flags);
}